// Round 3
// baseline (1608.543 us; speedup 1.0000x reference)
//
#include <hip/hip_runtime.h>

// ---------------------------------------------------------------------------
// WindowAttention on MI355X (gfx950) — fused per-window design.
// B_=4096 windows, S=49 (7x7), D=384, H=6 heads, hd=64, Wn=64 masks.
//
// Workspace use is tiny (~4.9 MB): bf16 transposed weights + bias/mask table.
// (Prior 622 MB layout is the prime suspect for the container faults.)
//
// fused kernel, one block (4 waves) per window:
//   per head h:
//     QKV GEMM  : A = x (fp32, converted to bf16 on the fly, pad rows zeroed)
//                 B = wqkv_t strips staged to LDS via global_load_lds(16B)
//     epilogue  : +bias, q*0.125, -> Qs/Ks/Vs in LDS
//     QK^T MFMA -> Sc (fp32) -> softmax(+bias+mask) -> Pb (bf16)
//     PV MFMA   -> O_h -> Ob (LDS, aliases Pb region rows are own-wave)
//     proj part : pacc += O_h @ proj_w[h*64:(h+1)*64, :]  (register acc)
//   epilogue: out = pacc + proj_b (fp32)
// ---------------------------------------------------------------------------

typedef __attribute__((ext_vector_type(8))) short bfx8;  // 8 x bf16
typedef __attribute__((ext_vector_type(4))) float fx4;   // MFMA accumulator

typedef const __attribute__((address_space(1))) void* gptr_t;
typedef __attribute__((address_space(3))) void* lptr_t;

__device__ __forceinline__ short f2bf(float f) {
  union { float f; unsigned u; } v;
  v.f = f;
  unsigned r = v.u + 0x7fffu + ((v.u >> 16) & 1u);  // round-to-nearest-even
  return (short)(r >> 16);
}

// ------------------------------ prep kernels -------------------------------

// wt[n][k] = bf16(w[k][n]); w is K x N row-major.
__global__ __launch_bounds__(256) void convT_kernel(const float* __restrict__ w,
                                                    short* __restrict__ wt, int N, int K) {
  int i = blockIdx.x * 256 + threadIdx.x;
  if (i < N * K) {
    int n = i / K, k = i - n * K;
    wt[i] = f2bf(w[(size_t)k * N + n]);
  }
}

// bm[(w*6+h)*2401 + rc] = bias_table[rel_index[rc]*6 + h] + mask[w*2401 + rc]
__global__ __launch_bounds__(256) void bm_kernel(const float* __restrict__ mask,
                                                 const float* __restrict__ bias_table,
                                                 const int* __restrict__ rel_index,
                                                 float* __restrict__ bm) {
  int i = blockIdx.x * 256 + threadIdx.x;
  if (i < 64 * 6 * 2401) {
    int rc = i % 2401;
    int wh = i / 2401;
    int h = wh % 6, w = wh / 6;
    bm[i] = bias_table[rel_index[rc] * 6 + h] + mask[w * 2401 + rc];
  }
}

// ------------------------------ fused kernel -------------------------------

__global__ __launch_bounds__(256, 2) void fused_attn_kernel(
    const float* __restrict__ x,        // [4096*49][384] fp32
    const short* __restrict__ wqkv_t,   // [1152][384] bf16 (n-major)
    const short* __restrict__ wproj_t,  // [384][384] bf16 (n-major)
    const float* __restrict__ qkv_b,    // [1152]
    const float* __restrict__ proj_b,   // [384]
    const float* __restrict__ bm,       // [64][6][49][49]
    float* __restrict__ out) {          // [4096*49][384] fp32
  // LDS: 9216*2 (Qs,Ks) + 8448 (Vs) + 16640 (Sc) + 9216 (Pb/Ob) + 12288 (Ws)
  //    = 65,024 B  (< 64 KB)
  __shared__ __align__(16) short Qs[64 * 72];
  __shared__ __align__(16) short Ks[64 * 72];
  __shared__ __align__(16) short Vs[64 * 66];
  __shared__ __align__(16) float Sc[64 * 65];
  __shared__ __align__(16) short Pb[64 * 72];   // P, then reused as Ob (O_h)
  __shared__ __align__(16) short Ws[192 * 32];  // weight staging tile

  const int tid = threadIdx.x;
  const int lane = tid & 63, wid = tid >> 6;
  const int l15 = lane & 15, q4 = lane >> 4;
  const int b = blockIdx.x, w = b & 63;
  const float* xw = x + (size_t)b * 49 * 384;
  const float* bmp_base = bm + ((size_t)(w * 6)) * 2401;

  const fx4 zero = {0.f, 0.f, 0.f, 0.f};
  fx4 pacc[24];  // proj accumulator: M-tile `wid`, all 24 N-tiles of 384
#pragma unroll
  for (int i = 0; i < 24; i++) pacc[i] = zero;

  const int arow = wid * 16 + l15;  // A-operand row this lane reads (x / Ob)
  const int crow = wid * 16 + q4 * 4;  // C-fragment base row this lane holds

  for (int h = 0; h < 6; ++h) {
    const int h64 = h * 64;

    // ---------------- QKV GEMM for head h: [64x384] @ [192x384]^T ----------
    fx4 qacc[12];
#pragma unroll
    for (int i = 0; i < 12; i++) qacc[i] = zero;

    for (int kt = 0; kt < 12; ++kt) {
      // A: x[arow][kt*32 + q4*8 .. +8] fp32, zero for pad rows
      float4 a0 = {0.f, 0.f, 0.f, 0.f}, a1 = {0.f, 0.f, 0.f, 0.f};
      if (arow < 49) {
        const float4* ap = (const float4*)(xw + (size_t)arow * 384 + kt * 32 + q4 * 8);
        a0 = ap[0];
        a1 = ap[1];
      }
      // B: stage [192 n][32 k] of wqkv_t (3 strips of 64 head-cols)
#pragma unroll
      for (int r = 0; r < 3; ++r) {
        const int off = r * 4096 + tid * 16;  // byte offset into Ws
        const int srow = off >> 6;            // 0..191 (64B per row)
        const int ce = (off & 63) >> 1;       // element within 32-elem chunk
        const int n = (srow >> 6) * 384 + h64 + (srow & 63);
        __builtin_amdgcn_global_load_lds(
            (gptr_t)(wqkv_t + (size_t)n * 384 + kt * 32 + ce),
            (lptr_t)((char*)Ws + off), 16, 0, 0);
      }
      __syncthreads();

      bfx8 af;
      af[0] = f2bf(a0.x); af[1] = f2bf(a0.y); af[2] = f2bf(a0.z); af[3] = f2bf(a0.w);
      af[4] = f2bf(a1.x); af[5] = f2bf(a1.y); af[6] = f2bf(a1.z); af[7] = f2bf(a1.w);
#pragma unroll
      for (int nt = 0; nt < 12; ++nt) {
        const bfx8 bf = *(const bfx8*)&Ws[(nt * 16 + l15) * 32 + q4 * 8];
        qacc[nt] = __builtin_amdgcn_mfma_f32_16x16x32_bf16(af, bf, qacc[nt], 0, 0, 0);
      }
      __syncthreads();
    }

    // epilogue: +bias, scale q, write Qs/Ks/Vs (bf16)
#pragma unroll
    for (int nt = 0; nt < 12; ++nt) {
      const int which = nt >> 2;            // 0=q 1=k 2=v
      const int e = (nt & 3) * 16 + l15;    // 0..63 within head
      const float bias = qkv_b[which * 384 + h64 + e];
      const float sc = (which == 0) ? 0.125f : 1.0f;
#pragma unroll
      for (int rr = 0; rr < 4; ++rr) {
        const int row = crow + rr;
        const short v = f2bf((qacc[nt][rr] + bias) * sc);
        if (which == 0)      Qs[row * 72 + e] = v;
        else if (which == 1) Ks[row * 72 + e] = v;
        else                 Vs[row * 66 + e] = v;
      }
    }
    __syncthreads();

    // ---------------- S = Q @ K^T (64x64, rows wid*16..) -------------------
    fx4 sacc[4];
#pragma unroll
    for (int i = 0; i < 4; i++) sacc[i] = zero;
#pragma unroll
    for (int ks = 0; ks < 2; ++ks) {
      const bfx8 aq = *(const bfx8*)&Qs[arow * 72 + ks * 32 + q4 * 8];
#pragma unroll
      for (int nt = 0; nt < 4; ++nt) {
        const bfx8 bk = *(const bfx8*)&Ks[(nt * 16 + l15) * 72 + ks * 32 + q4 * 8];
        sacc[nt] = __builtin_amdgcn_mfma_f32_16x16x32_bf16(aq, bk, sacc[nt], 0, 0, 0);
      }
    }
#pragma unroll
    for (int nt = 0; nt < 4; ++nt)
#pragma unroll
      for (int rr = 0; rr < 4; ++rr)
        Sc[(crow + rr) * 65 + nt * 16 + l15] = sacc[nt][rr];
    __syncthreads();

    // ---------------- softmax (+bias+mask), P -> Pb bf16 -------------------
    {
      const int r = tid >> 2, j = tid & 3;
      if (r < 49) {
        const float* bmp = bmp_base + (size_t)h * 2401 + r * 49;
        float mx = -1e30f;
        for (int c = j; c < 49; c += 4) {
          const float s = Sc[r * 65 + c] + bmp[c];
          Sc[r * 65 + c] = s;
          mx = fmaxf(mx, s);
        }
        mx = fmaxf(mx, __shfl_xor(mx, 1));
        mx = fmaxf(mx, __shfl_xor(mx, 2));
        float sum = 0.f;
        for (int c = j; c < 49; c += 4) {
          const float p = __expf(Sc[r * 65 + c] - mx);
          Sc[r * 65 + c] = p;
          sum += p;
        }
        sum += __shfl_xor(sum, 1);
        sum += __shfl_xor(sum, 2);
        const float inv = 1.f / sum;
        for (int c = j; c < 49; c += 4) Pb[r * 72 + c] = f2bf(Sc[r * 65 + c] * inv);
        for (int c = 49 + j; c < 64; c += 4) Pb[r * 72 + c] = 0;
      } else {
        for (int c = j; c < 64; c += 4) Pb[r * 72 + c] = 0;
      }
    }
    __syncthreads();

    // ---------------- O_h = P @ V (64x64) ----------------------------------
    fx4 oacc[4];
#pragma unroll
    for (int i = 0; i < 4; i++) oacc[i] = zero;
#pragma unroll
    for (int ks = 0; ks < 2; ++ks) {
      const bfx8 ap = *(const bfx8*)&Pb[arow * 72 + ks * 32 + q4 * 8];
#pragma unroll
      for (int nt = 0; nt < 4; ++nt) {
        bfx8 bv;
#pragma unroll
        for (int jj = 0; jj < 8; ++jj)
          bv[jj] = Vs[(ks * 32 + q4 * 8 + jj) * 66 + nt * 16 + l15];
        oacc[nt] = __builtin_amdgcn_mfma_f32_16x16x32_bf16(ap, bv, oacc[nt], 0, 0, 0);
      }
    }
    // O_h -> Ob (reuse Pb; each wave only touches its own 16-row strip)
#pragma unroll
    for (int nt = 0; nt < 4; ++nt)
#pragma unroll
      for (int rr = 0; rr < 4; ++rr)
        Pb[(crow + rr) * 72 + nt * 16 + l15] = f2bf(oacc[nt][rr]);

    // ---------------- pacc += O_h @ proj_w[h*64.. , :] ---------------------
#pragma unroll
    for (int n0 = 0; n0 < 2; ++n0) {
#pragma unroll
      for (int ks = 0; ks < 2; ++ks) {
#pragma unroll
        for (int r = 0; r < 3; ++r) {
          const int off = r * 4096 + tid * 16;
          const int srow = off >> 6;
          const int ce = (off & 63) >> 1;
          const int n = n0 * 192 + srow;
          __builtin_amdgcn_global_load_lds(
              (gptr_t)(wproj_t + (size_t)n * 384 + h64 + ks * 32 + ce),
              (lptr_t)((char*)Ws + off), 16, 0, 0);
        }
        __syncthreads();
        const bfx8 ao = *(const bfx8*)&Pb[arow * 72 + ks * 32 + q4 * 8];
#pragma unroll
        for (int ntl = 0; ntl < 12; ++ntl) {
          const bfx8 bp = *(const bfx8*)&Ws[(ntl * 16 + l15) * 32 + q4 * 8];
          pacc[n0 * 12 + ntl] =
              __builtin_amdgcn_mfma_f32_16x16x32_bf16(ao, bp, pacc[n0 * 12 + ntl], 0, 0, 0);
        }
        __syncthreads();
      }
    }
  }  // heads

  // ---------------- out = pacc + proj_b ------------------------------------
#pragma unroll
  for (int nt = 0; nt < 24; ++nt) {
    const int n = nt * 16 + l15;
    const float bias = proj_b[n];
#pragma unroll
    for (int rr = 0; rr < 4; ++rr) {
      const int s = crow + rr;
      if (s < 49) out[((size_t)b * 49 + s) * 384 + n] = pacc[nt][rr] + bias;
    }
  }
}

// ------------------------------- launcher ----------------------------------

extern "C" void kernel_launch(void* const* d_in, const int* in_sizes, int n_in,
                              void* d_out, int out_size, void* d_ws, size_t ws_size,
                              hipStream_t stream) {
  const float* x       = (const float*)d_in[0];
  const float* mask    = (const float*)d_in[1];
  const float* qkv_w   = (const float*)d_in[2];
  const float* qkv_b   = (const float*)d_in[3];
  const float* proj_w  = (const float*)d_in[4];
  const float* proj_b  = (const float*)d_in[5];
  const float* bias_t  = (const float*)d_in[6];
  const int*   rel_idx = (const int*)d_in[7];
  float* out = (float*)d_out;

  char* ws = (char*)d_ws;
  short* wqkv_t  = (short*)(ws);                       // 1152*384*2 = 884,736 B
  short* wproj_t = (short*)(ws + 884736);              //  384*384*2 = 294,912 B
  float* bmw     = (float*)(ws + 884736 + 294912);     // 64*6*49*49*4 = 3,687,936 B
  // total workspace: 4,867,584 B (~4.9 MB)

  convT_kernel<<<1728, 256, 0, stream>>>(qkv_w, wqkv_t, 1152, 384);
  convT_kernel<<<576, 256, 0, stream>>>(proj_w, wproj_t, 384, 384);
  bm_kernel<<<3602, 256, 0, stream>>>(mask, bias_t, rel_idx, bmw);

  fused_attn_kernel<<<4096, 256, 0, stream>>>(x, wqkv_t, wproj_t, qkv_b, proj_b,
                                              bmw, out);
}